// Round 1
// baseline (688.635 us; speedup 1.0000x reference)
//
#include <hip/hip_runtime.h>

// MapNet forward: project image features into a 128x128 egocentric map via
// depth, scatter-max over features, empty cells -> 0.
//
// bs=64, F=64, h=w=64, H=W=256, K=4, s=128
// fx=fy=128, cx=cy=128, EPS=-1e16

#define BS 64
#define FDIM 64
#define S 128
#define EPS_F (-1e16f)

// ---------------- init: fill output with EPS ----------------
__global__ void init_eps(float4* __restrict__ out, int n4) {
    int i = blockIdx.x * blockDim.x + threadIdx.x;
    const float4 v = make_float4(EPS_F, EPS_F, EPS_F, EPS_F);
    int stride = gridDim.x * blockDim.x;
    for (; i < n4; i += stride) out[i] = v;
}

// ---------------- float atomic max (sign-split trick) ----------------
__device__ __forceinline__ void atomicMaxF(float* addr, float val) {
    // canonicalize -0.0 -> +0.0 so ordering stays consistent
    if (__float_as_uint(val) == 0x80000000u) val = 0.0f;
    if (val >= 0.0f) {
        atomicMax(reinterpret_cast<int*>(addr), __float_as_int(val));
    } else {
        atomicMin(reinterpret_cast<unsigned int*>(addr), __float_as_uint(val));
    }
}

// ---------------- scatter: one thread per (batch, pixel) ----------------
__global__ void scatter_max(const float* __restrict__ img,
                            const float* __restrict__ depth,
                            float* __restrict__ out) {
    int tid = blockIdx.x * blockDim.x + threadIdx.x;  // 64*4096 threads
    int b = tid >> 12;          // batch
    int p = tid & 4095;         // pixel within 64x64 feature map
    int i = p >> 6;             // feature row
    int j = p & 63;             // feature col
    int r = i * 4 + 2;          // image row (K=4, K/2=2)
    int c = j * 4 + 2;          // image col

    // depth channel 0 only: (bs,3,256,256)
    float Z = depth[(size_t)b * 3 * 256 * 256 + r * 256 + c] * 10.0f;
    // X = ((c - cx)/fx) * Z ; (c-128)/128 is exact (pow2 divide)
    float X = (((float)c - 128.0f) / 128.0f) * Z;

    bool valid = fabsf(Z) > 0.8f;
    // match JAX exactly: divide by float32(0.1), round-half-even
    float zg = rintf(-(Z / 0.1f) + 127.0f);
    float xg = rintf(X / 0.1f + 63.5f);
    int zi = (int)zg;
    int xi = (int)xg;

    bool invalid = (zi >= S) | (xi >= S) | (zi < 0) | (xi < 0) | (!valid);
    if (invalid) return;  // reference's EPS write to cell 0 is a max no-op

    int cell = zi * S + xi;
    const float* fp = img + (size_t)b * FDIM * 4096 + p;
    float* op = out + (size_t)b * FDIM * (S * S) + cell;

    #pragma unroll 8
    for (int f = 0; f < FDIM; ++f) {
        atomicMaxF(op + (size_t)f * (S * S), fp[(size_t)f * 4096]);
    }
}

// ---------------- finalize: EPS -> 0 ----------------
__global__ void finalize_eps(float4* __restrict__ out, int n4) {
    int i = blockIdx.x * blockDim.x + threadIdx.x;
    int stride = gridDim.x * blockDim.x;
    for (; i < n4; i += stride) {
        float4 v = out[i];
        v.x = (v.x == EPS_F) ? 0.0f : v.x;
        v.y = (v.y == EPS_F) ? 0.0f : v.y;
        v.z = (v.z == EPS_F) ? 0.0f : v.z;
        v.w = (v.w == EPS_F) ? 0.0f : v.w;
        out[i] = v;
    }
}

extern "C" void kernel_launch(void* const* d_in, const int* in_sizes, int n_in,
                              void* d_out, int out_size, void* d_ws, size_t ws_size,
                              hipStream_t stream) {
    const float* img = (const float*)d_in[0];    // (64,64,64,64)
    const float* depth = (const float*)d_in[1];  // (64,3,256,256)
    float* out = (float*)d_out;                  // (64,64,128,128)

    const int n = BS * FDIM * S * S;             // 67,108,864 floats
    const int n4 = n / 4;                        // 16,777,216 float4

    init_eps<<<2048, 256, 0, stream>>>((float4*)out, n4);

    const int npix = BS * 4096;                  // 262,144 threads
    scatter_max<<<npix / 256, 256, 0, stream>>>(img, depth, out);

    finalize_eps<<<2048, 256, 0, stream>>>((float4*)out, n4);
}

// Round 2
// 95.499 us; speedup vs baseline: 7.2109x; 7.2109x over previous
//
#include <hip/hip_runtime.h>

// MapNet forward, fused single kernel.
// One block per (batch, feature): scatter-max 4096 pixels into a 64KB LDS
// grid (monotone int encoding -> single LDS atomicMax), then stream out with
// EPS->0 conversion fused. No global atomics, no init/finalize passes.
//
// bs=64, F=64, h=w=64, H=W=256, K=4, s=128, fx=fy=cx=cy=128, EPS=-1e16

#define S 128
#define EPS_F (-1e16f)

// monotone float<->int mapping (involution): order-preserving under signed
// integer comparison. x>=0: bits unchanged; x<0: flip magnitude bits.
__device__ __forceinline__ int enc(float x) {
    int i = __float_as_int(x);
    return i ^ ((i >> 31) & 0x7fffffff);
}
__device__ __forceinline__ float dec(int k) {
    return __int_as_float(k ^ ((k >> 31) & 0x7fffffff));
}

__global__ __launch_bounds__(1024, 8) void mapnet_fused(
        const float* __restrict__ img,    // (64,64,64,64)
        const float* __restrict__ depth,  // (64,3,256,256)
        float* __restrict__ out) {        // (64,64,128,128)
    __shared__ int grid[S * S];           // 64 KB

    const int t = threadIdx.x;            // 0..1023
    const int bf = blockIdx.x;            // b*64 + f
    const int b = bf >> 6;

    // encoded EPS (compile-time foldable)
    const int EPSK = enc(EPS_F);

    // ---- init LDS grid to enc(EPS) ----
    int4* g4 = reinterpret_cast<int4*>(grid);
    const int4 epsv = make_int4(EPSK, EPSK, EPSK, EPSK);
    #pragma unroll
    for (int k = 0; k < 4; ++k) g4[t + k * 1024] = epsv;
    __syncthreads();

    const float* dp = depth + (size_t)b * 3 * 256 * 256;  // channel 0 plane
    const float* ip = img + (size_t)bf * 4096;

    // ---- scatter: 4 pixels per thread, wave-coalesced (p = t + k*1024) ----
    #pragma unroll
    for (int k = 0; k < 4; ++k) {
        int p = t + k * 1024;
        int r = (p >> 6) * 4 + 2;   // image row
        int c = (p & 63) * 4 + 2;   // image col

        float Z = dp[r * 256 + c] * 10.0f;            // depth -> meters
        float v = ip[p];                               // feature value

        // match JAX arithmetic exactly: f32 divide by 0.1f, rint (half-even)
        bool valid = fabsf(Z) > 0.8f;
        float X = (((float)c - 128.0f) * (1.0f / 128.0f)) * Z;  // /128 exact
        int zi = (int)rintf(-(Z / 0.1f) + 127.0f);
        int xi = (int)rintf(X / 0.1f + 63.5f);

        bool inval = (zi >= S) | (xi >= S) | (zi < 0) | (xi < 0) | (!valid);
        if (!inval) atomicMax(&grid[zi * S + xi], enc(v));
    }
    __syncthreads();

    // ---- writeout: decode, EPS->0, streaming float4 stores ----
    float4* o4 = reinterpret_cast<float4*>(out) + (size_t)bf * 4096;
    #pragma unroll
    for (int k = 0; k < 4; ++k) {
        int idx = t + k * 1024;
        int4 gk = g4[idx];
        float4 o;
        o.x = (gk.x == EPSK) ? 0.0f : dec(gk.x);
        o.y = (gk.y == EPSK) ? 0.0f : dec(gk.y);
        o.z = (gk.z == EPSK) ? 0.0f : dec(gk.z);
        o.w = (gk.w == EPSK) ? 0.0f : dec(gk.w);
        o4[idx] = o;
    }
}

extern "C" void kernel_launch(void* const* d_in, const int* in_sizes, int n_in,
                              void* d_out, int out_size, void* d_ws, size_t ws_size,
                              hipStream_t stream) {
    const float* img = (const float*)d_in[0];    // (64,64,64,64)
    const float* depth = (const float*)d_in[1];  // (64,3,256,256)
    float* out = (float*)d_out;                  // (64,64,128,128)

    mapnet_fused<<<64 * 64, 1024, 0, stream>>>(img, depth, out);
}

// Round 4
// 95.101 us; speedup vs baseline: 7.2411x; 1.0042x over previous
//
#include <hip/hip_runtime.h>

// MapNet forward, fused single kernel (R3 = R2 with ext_vector types for
// nontemporal builtins).
// One block per (batch, feature): scatter-max 4096 pixels into a 64KB LDS
// grid (monotone int encoding -> LDS atomicMax), stream out with EPS->0.
// float4 img loads, prefetch-before-init, XCD-aware block swizzle,
// nontemporal load/store.
//
// bs=64, F=64, h=w=64, H=W=256, K=4, s=128, fx=fy=cx=cy=128, EPS=-1e16

#define S 128
#define EPS_F (-1e16f)

typedef __attribute__((ext_vector_type(4))) float f32x4;
typedef __attribute__((ext_vector_type(4))) int i32x4;

// monotone float<->int mapping (involution): order-preserving under signed
// integer comparison. x>=0: bits unchanged; x<0: flip magnitude bits.
__device__ __forceinline__ int enc(float x) {
    int i = __float_as_int(x);
    return i ^ ((i >> 31) & 0x7fffffff);
}
__device__ __forceinline__ float dec(int k) {
    return __int_as_float(k ^ ((k >> 31) & 0x7fffffff));
}

__global__ __launch_bounds__(1024, 8) void mapnet_fused(
        const float* __restrict__ img,    // (64,64,64,64)
        const float* __restrict__ depth,  // (64,3,256,256)
        float* __restrict__ out) {        // (64,64,128,128)
    __shared__ int grid[S * S];           // 64 KB -> 2 blocks/CU (LDS-limited)

    const int t = threadIdx.x;            // 0..1023

    // XCD swizzle: give each XCD a contiguous run of bf so all 64 feature-
    // blocks of a batch share one XCD's L2 (depth-plane reuse). Bijective:
    // 4096 % 8 == 0.
    const int orig = blockIdx.x;
    const int bf = (orig & 7) * 512 + (orig >> 3);
    const int b = bf >> 6;

    // ---- prefetch global loads BEFORE LDS init (latency hides under init) ----
    const f32x4* ip4 = reinterpret_cast<const f32x4*>(img) + (size_t)bf * 1024;
    f32x4 iv = __builtin_nontemporal_load(ip4 + t);   // pixels 4t..4t+3

    const float* dp = depth + (size_t)b * 3 * 256 * 256;  // channel-0 plane
    const int p0 = 4 * t;
    const int r = (p0 >> 6) * 4 + 2;        // same image row for all 4 pixels
    const int cbase = (p0 & 63) * 4 + 2;    // image col of pixel 4t
    const float* drow = dp + r * 256 + cbase;
    float z0 = drow[0];
    float z1 = drow[4];
    float z2 = drow[8];
    float z3 = drow[12];

    // ---- init LDS grid to enc(EPS) ----
    const int EPSK = enc(EPS_F);
    i32x4* g4 = reinterpret_cast<i32x4*>(grid);
    const i32x4 epsv = {EPSK, EPSK, EPSK, EPSK};
    #pragma unroll
    for (int k = 0; k < 4; ++k) g4[t + k * 1024] = epsv;
    __syncthreads();

    // ---- scatter: 4 consecutive pixels per thread ----
    float zs[4] = {z0, z1, z2, z3};
    float vs[4] = {iv.x, iv.y, iv.z, iv.w};
    #pragma unroll
    for (int j = 0; j < 4; ++j) {
        float Z = zs[j] * 10.0f;                       // depth -> meters
        int c = cbase + 4 * j;
        bool valid = fabsf(Z) > 0.8f;
        // match JAX exactly: f32 divide by 0.1f, rint (round-half-even);
        // (c-128)/128 exact via pow2 multiply
        float X = (((float)c - 128.0f) * (1.0f / 128.0f)) * Z;
        int zi = (int)rintf(-(Z / 0.1f) + 127.0f);
        int xi = (int)rintf(X / 0.1f + 63.5f);
        bool inval = (zi >= S) | (xi >= S) | (zi < 0) | (xi < 0) | (!valid);
        if (!inval) atomicMax(&grid[zi * S + xi], enc(vs[j]));
    }
    __syncthreads();

    // ---- writeout: decode, EPS->0, nontemporal float4 stores ----
    f32x4* o4 = reinterpret_cast<f32x4*>(out) + (size_t)bf * 4096;
    #pragma unroll
    for (int k = 0; k < 4; ++k) {
        int idx = t + k * 1024;
        i32x4 gk = g4[idx];
        f32x4 o;
        o.x = (gk.x == EPSK) ? 0.0f : dec(gk.x);
        o.y = (gk.y == EPSK) ? 0.0f : dec(gk.y);
        o.z = (gk.z == EPSK) ? 0.0f : dec(gk.z);
        o.w = (gk.w == EPSK) ? 0.0f : dec(gk.w);
        __builtin_nontemporal_store(o, o4 + idx);
    }
}

extern "C" void kernel_launch(void* const* d_in, const int* in_sizes, int n_in,
                              void* d_out, int out_size, void* d_ws, size_t ws_size,
                              hipStream_t stream) {
    const float* img = (const float*)d_in[0];    // (64,64,64,64)
    const float* depth = (const float*)d_in[1];  // (64,3,256,256)
    float* out = (float*)d_out;                  // (64,64,128,128)

    mapnet_fused<<<64 * 64, 1024, 0, stream>>>(img, depth, out);
}

// Round 5
// 86.704 us; speedup vs baseline: 7.9424x; 1.0969x over previous
//
#include <hip/hip_runtime.h>

// MapNet forward (R4): persistent feature-loop blocks.
// Block = (batch, group of 8 features), 1024 threads, one 64KB LDS grid.
// Pixel->cell map computed ONCE per block (depth-only), reused for all 8
// features. Per feature: scatter (LDS atomicMax, monotone int encoding) ->
// barrier -> writeout + reinit-to-EPS fused (continuous store stream) ->
// barrier. Next feature's img prefetched under writeout.
//
// bs=64, F=64, h=w=64, H=W=256, K=4, s=128, fx=fy=cx=cy=128, EPS=-1e16

#define S 128
#define EPS_F (-1e16f)

typedef __attribute__((ext_vector_type(4))) float f32x4;
typedef __attribute__((ext_vector_type(4))) int i32x4;

// monotone float<->int involution: order-preserving under signed int compare
__device__ __forceinline__ int enc(float x) {
    int i = __float_as_int(x);
    return i ^ ((i >> 31) & 0x7fffffff);
}
__device__ __forceinline__ float dec(int k) {
    return __int_as_float(k ^ ((k >> 31) & 0x7fffffff));
}

__global__ __launch_bounds__(1024, 8) void mapnet_persist(
        const float* __restrict__ img,    // (64,64,64,64)
        const float* __restrict__ depth,  // (64,3,256,256)
        float* __restrict__ out) {        // (64,64,128,128)
    __shared__ int grid[S * S];           // 64 KB -> 2 blocks/CU

    const int t = threadIdx.x;            // 0..1023

    // swizzle: all 8 feature-groups of a batch land on one XCD (depth reuse)
    const int j = blockIdx.x;             // 0..511
    const int xcd = j & 7;
    const int slot = j >> 3;              // 0..63
    const int b = xcd * 8 + (slot >> 3);  // batch
    const int f0 = (slot & 7) * 8;        // first feature of this block

    // ---- pixel->cell map, computed once (depth-only, feature-independent) ----
    const float* dp = depth + (size_t)b * 3 * 256 * 256;  // channel-0 plane
    const int p0 = 4 * t;                  // first of 4 consecutive pixels
    const int r = (p0 >> 6) * 4 + 2;       // image row (same for all 4)
    const int cbase = (p0 & 63) * 4 + 2;   // image col of pixel p0
    const float* drow = dp + r * 256 + cbase;
    int cell[4];
    #pragma unroll
    for (int q = 0; q < 4; ++q) {
        float Z = drow[4 * q] * 10.0f;                  // depth -> meters
        int c = cbase + 4 * q;
        bool valid = fabsf(Z) > 0.8f;
        // match JAX exactly: f32 div by 0.1f, rint (half-even); /128 exact
        float X = (((float)c - 128.0f) * (1.0f / 128.0f)) * Z;
        int zi = (int)rintf(-(Z / 0.1f) + 127.0f);
        int xi = (int)rintf(X / 0.1f + 63.5f);
        bool inval = (zi >= S) | (xi >= S) | (zi < 0) | (xi < 0) | (!valid);
        cell[q] = inval ? -1 : (zi * S + xi);
    }

    // ---- prologue: init grid to enc(EPS); prefetch first feature ----
    const int EPSK = enc(EPS_F);
    i32x4* g4 = reinterpret_cast<i32x4*>(grid);
    const i32x4 epsv = {EPSK, EPSK, EPSK, EPSK};
    #pragma unroll
    for (int m = 0; m < 4; ++m) g4[t + m * 1024] = epsv;

    const f32x4* imgb = reinterpret_cast<const f32x4*>(img)
                        + (size_t)(b * 64 + f0) * 1024;   // 1024 f32x4 / feature
    f32x4 iv = __builtin_nontemporal_load(imgb + t);      // pixels 4t..4t+3
    __syncthreads();

    f32x4* outb = reinterpret_cast<f32x4*>(out)
                  + (size_t)(b * 64 + f0) * 4096;         // 4096 f32x4 / feature

    for (int k = 0; k < 8; ++k) {
        // ---- scatter feature f0+k into LDS grid ----
        float vs[4] = {iv.x, iv.y, iv.z, iv.w};
        #pragma unroll
        for (int q = 0; q < 4; ++q)
            if (cell[q] >= 0) atomicMax(&grid[cell[q]], enc(vs[q]));

        // prefetch next feature (latency hides under writeout below)
        f32x4 ivn = iv;
        if (k < 7) ivn = __builtin_nontemporal_load(imgb + (size_t)(k + 1) * 1024 + t);

        __syncthreads();  // scatter complete

        // ---- writeout + reinit fused ----
        f32x4* o4 = outb + (size_t)k * 4096;
        #pragma unroll
        for (int m = 0; m < 4; ++m) {
            int idx = t + m * 1024;
            i32x4 gk = g4[idx];
            g4[idx] = epsv;               // reinit for next feature
            f32x4 o;
            o.x = (gk.x == EPSK) ? 0.0f : dec(gk.x);
            o.y = (gk.y == EPSK) ? 0.0f : dec(gk.y);
            o.z = (gk.z == EPSK) ? 0.0f : dec(gk.z);
            o.w = (gk.w == EPSK) ? 0.0f : dec(gk.w);
            __builtin_nontemporal_store(o, o4 + idx);
        }

        __syncthreads();  // reinit complete before next scatter
        iv = ivn;
    }
}

extern "C" void kernel_launch(void* const* d_in, const int* in_sizes, int n_in,
                              void* d_out, int out_size, void* d_ws, size_t ws_size,
                              hipStream_t stream) {
    const float* img = (const float*)d_in[0];    // (64,64,64,64)
    const float* depth = (const float*)d_in[1];  // (64,3,256,256)
    float* out = (float*)d_out;                  // (64,64,128,128)

    mapnet_persist<<<512, 1024, 0, stream>>>(img, depth, out);
}